// Round 5
// baseline (629.632 us; speedup 1.0000x reference)
//
#include <hip/hip_runtime.h>
#include <hip/hip_bf16.h>

// DiagonalWindowAttention fused MFMA kernel (v3: reg-prefetch, 2 barriers/head,
// coalesced epilogue).
// One block per window (nw=2048), 256 threads = 4 waves, 3 blocks/CU.
//   phase 0 : LN stats per patch; stage gamma/beta; prefetch+pack head 0
//   head n  : LDS-stage from packed regs (Q/K swz [64][64], VT swz) ->
//             prefetch head n+1 -> sync -> QK^T MFMA -> bias+mask+softmax ->
//             P store (wave-private, lgkm fence) -> PV MFMA -> pre store
//             (wave-private) -> [odd n: lgkm fence + proj MFMA] -> sync
//   epilogue: +bias, per-wave LDS restage to gsq-contiguous rows, dwordx4 stores
//
// token grouping: p = wh*8+ww, s = sh*2+sw, seq g = wh*32+sh*16+ww*2+sw
// wave wv's 64 tokens map bijectively onto gsq in [64*wv, 64*wv+64).

#define TPB 256

// LDS byte offsets
#define Q0   0        // [64][64] bf16 swizzled (8 KB)
#define K0   8192
#define P0   16384
#define VT0  24576    // V^T per head: [n'=s*16+c][kp] bf16 swizzled (8 KB)
#define PR0  32768    // pre[256][32] bf16 (16 KB)
#define MU0  49152
#define RS0  49408
#define GA0  49664    // gamma fp32 [4][96]
#define BE0  51200    // beta  fp32 [4][96]
#define LDS_TOTAL 52736
// epilogue reuses [0, 25600): per-wave 6400 B at wv*6400 (after final barrier)

typedef __attribute__((ext_vector_type(8))) short short8;
typedef __attribute__((ext_vector_type(4))) float f32x4;

union FRAG { uint4 u4; short8 s8; unsigned short us[8]; };

__device__ __forceinline__ int seq_of(int p, int s) {
    return ((p >> 3) << 5) | ((s >> 1) << 4) | ((p & 7) << 1) | (s & 1);
}

// swizzled byte address of 16B slot in a [64][64] bf16 tile (128B rows)
#define SWZ(row, slot) (((row) << 7) + ((((slot) ^ ((row) & 7))) << 4))

#define LGKM_FENCE() do { \
    asm volatile("s_waitcnt lgkmcnt(0)" ::: "memory"); \
    __builtin_amdgcn_sched_barrier(0); } while (0)

__device__ __forceinline__ unsigned short f2b(float x) {
    union { __hip_bfloat16 h; unsigned short u; } z;
    z.h = __float2bfloat16(x);
    return z.u;
}

__device__ __forceinline__ uint4 pack8(const float* v) {
    union { uint4 u4; unsigned short us[8]; } z;
#pragma unroll
    for (int i = 0; i < 8; ++i) z.us[i] = f2b(v[i]);
    return z.u4;
}

// load 16 floats (4x float4), optionally LN, pack to 2x uint4 (bf16 x16)
__device__ __forceinline__ void load_pack_ln(const float* src, const float* ga,
                                             const float* be, float mu, float rs,
                                             uint4* dst) {
    float v[16];
#pragma unroll
    for (int i = 0; i < 4; ++i) {
        float4 x = ((const float4*)src)[i];
        v[4 * i] = x.x; v[4 * i + 1] = x.y; v[4 * i + 2] = x.z; v[4 * i + 3] = x.w;
    }
#pragma unroll
    for (int i = 0; i < 16; ++i)
        v[i] = ((v[i] - mu) * rs * ga[i] + be[i]) * 0.125f;
    dst[0] = pack8(v);
    dst[1] = pack8(v + 8);
}

__device__ __forceinline__ void load_pack(const float* src, uint4* dst) {
    float v[16];
#pragma unroll
    for (int i = 0; i < 4; ++i) {
        float4 x = ((const float4*)src)[i];
        v[4 * i] = x.x; v[4 * i + 1] = x.y; v[4 * i + 2] = x.z; v[4 * i + 3] = x.w;
    }
    dst[0] = pack8(v);
    dst[1] = pack8(v + 8);
}

__global__ __launch_bounds__(TPB, 3)
void dwa_mfma(const float* __restrict__ gq,
              const float* __restrict__ gk,
              const float* __restrict__ gv,
              const float* __restrict__ gmask,
              const float* __restrict__ gbt,
              const float* __restrict__ ggamma,
              const float* __restrict__ gbeta,
              const float* __restrict__ gpw,
              const float* __restrict__ gpb,
              float* __restrict__ gout,
              int nwm)
{
    __shared__ __align__(16) unsigned char Lraw[LDS_TOTAL];
    char* L = (char*)Lraw;

    const int w = blockIdx.x;
    const int t = threadIdx.x;
    const int lane = t & 63, wv = t >> 6;
    const int r15 = lane & 15, gsl = lane >> 4;

    const int p_a = t >> 2, s_a = t & 3;
    const int g_a = seq_of(p_a, s_a);
    const size_t rowbase = ((size_t)w * 256 + g_a) * 96;
    const int mbase = (w % nwm) * 4096;

    float* s_mu = (float*)(L + MU0);
    float* s_rs = (float*)(L + RS0);
    float* s_ga = (float*)(L + GA0);
    float* s_be = (float*)(L + BE0);

    // ---------------- phase 0: LN stats + gamma/beta ----------------
    {
        const float4* qr = (const float4*)(gq + rowbase);
        float sum = 0.f, ssq = 0.f;
#pragma unroll
        for (int i = 0; i < 24; ++i) {
            float4 x = qr[i];
            sum += (x.x + x.y) + (x.z + x.w);
            ssq += (x.x * x.x + x.y * x.y) + (x.z * x.z + x.w * x.w);
        }
        sum += __shfl_xor(sum, 1); ssq += __shfl_xor(ssq, 1);
        sum += __shfl_xor(sum, 2); ssq += __shfl_xor(ssq, 2);
        if (s_a == 0) {
            float m_ = sum * (1.f / 384.f);
            s_mu[p_a] = m_;
            s_rs[p_a] = rsqrtf(ssq * (1.f / 384.f) - m_ * m_ + 1e-5f);
        }
    }
    for (int i = t; i < 384; i += TPB) {
        s_ga[i] = ggamma[i];
        s_be[i] = gbeta[i];
    }
    __syncthreads();
    const float mu = s_mu[p_a];
    const float rs = s_rs[p_a];
    const float* gaT = s_ga + s_a * 96;
    const float* beT = s_be + s_a * 96;

    const f32x4 zf = {0.f, 0.f, 0.f, 0.f};
    f32x4 pacc[4][6];
#pragma unroll
    for (int a = 0; a < 4; ++a)
#pragma unroll
        for (int b = 0; b < 6; ++b) pacc[a][b] = zf;

    const int qr0 = (wv << 4) + (gsl << 2);   // C-layout q-row base (+reg)

    // prefetch + pack head 0
    uint4 qp[2], kp[2], vp[2];
    load_pack_ln(gq + rowbase, gaT, beT, mu, rs, qp);
    load_pack(gk + rowbase, kp);
    load_pack(gv + rowbase, vp);

    for (int n = 0; n < 6; ++n) {
        // ------- stage from packed regs (Q/K row-major swz, V transposed) -------
        *(uint4*)(L + Q0 + SWZ(p_a, s_a * 2))     = qp[0];
        *(uint4*)(L + Q0 + SWZ(p_a, s_a * 2 + 1)) = qp[1];
        *(uint4*)(L + K0 + SWZ(p_a, s_a * 2))     = kp[0];
        *(uint4*)(L + K0 + SWZ(p_a, s_a * 2 + 1)) = kp[1];
#pragma unroll
        for (int h = 0; h < 2; ++h) {
            FRAG u; u.u4 = vp[h];
#pragma unroll
            for (int c = 0; c < 8; ++c) {
                const int np_ = s_a * 16 + h * 8 + c;   // n' row of VT
                *(unsigned short*)(L + VT0 + (np_ << 7) +
                    ((((p_a >> 3) ^ (np_ & 7))) << 4) + ((p_a & 7) << 1)) = u.us[c];
            }
        }
        // ------- issue prefetch for head n+1 (hidden under this head's compute) ---
        if (n < 5) {
            const int off = (n + 1) * 16;
            load_pack_ln(gq + rowbase + off, gaT + off, beT + off, mu, rs, qp);
            load_pack(gk + rowbase + off, kp);
            load_pack(gv + rowbase + off, vp);
        }
        __syncthreads();                     // barrier 1: staging visible

        // ---------------- QK^T ----------------
        FRAG a0, a1;
        a0.u4 = *(const uint4*)(L + Q0 + SWZ(wv * 16 + r15, gsl));
        a1.u4 = *(const uint4*)(L + Q0 + SWZ(wv * 16 + r15, 4 + gsl));
        f32x4 sacc[4];
#pragma unroll
        for (int tile = 0; tile < 4; ++tile) {
            FRAG b0, b1;
            b0.u4 = *(const uint4*)(L + K0 + SWZ(tile * 16 + r15, gsl));
            b1.u4 = *(const uint4*)(L + K0 + SWZ(tile * 16 + r15, 4 + gsl));
            sacc[tile] = __builtin_amdgcn_mfma_f32_16x16x32_bf16(a0.s8, b0.s8, zf, 0, 0, 0);
            sacc[tile] = __builtin_amdgcn_mfma_f32_16x16x32_bf16(a1.s8, b1.s8, sacc[tile], 0, 0, 0);
        }

        // ---------------- bias + mask + softmax + P store (wave-private) --------
#pragma unroll
        for (int r = 0; r < 4; ++r) {
            const int q = qr0 + r;
            const int iq = q >> 3, jq = q & 7;
            float vals[4];
            float mx = -3.0e38f;
#pragma unroll
            for (int tile = 0; tile < 4; ++tile) {
                const int kpx = (tile << 4) + r15;
                const int ik = kpx >> 3, jk = kpx & 7;
                const float bv = gbt[((iq - ik + 7) * 15 + (jq - jk + 7)) * 6 + n];
                const float mv = gmask[mbase + (q << 6) + kpx];
                float a = sacc[tile][r] + bv + mv;
                vals[tile] = a;
                mx = fmaxf(mx, a);
            }
            mx = fmaxf(mx, __shfl_xor(mx, 1));
            mx = fmaxf(mx, __shfl_xor(mx, 2));
            mx = fmaxf(mx, __shfl_xor(mx, 4));
            mx = fmaxf(mx, __shfl_xor(mx, 8));
            float sm = 0.f;
#pragma unroll
            for (int tile = 0; tile < 4; ++tile) {
                vals[tile] = __expf(vals[tile] - mx);
                sm += vals[tile];
            }
            sm += __shfl_xor(sm, 1);
            sm += __shfl_xor(sm, 2);
            sm += __shfl_xor(sm, 4);
            sm += __shfl_xor(sm, 8);
            const float inv = 1.0f / sm;
#pragma unroll
            for (int tile = 0; tile < 4; ++tile) {
                const int col = (tile << 4) + r15;
                *(unsigned short*)(L + P0 + (q << 7) +
                                   (((col >> 3) ^ (q & 7)) << 4) + ((col & 7) << 1))
                    = f2b(vals[tile] * inv);
            }
        }
        LGKM_FENCE();                        // P rows are wave-private

        // ---------------- PV: B-frags from VT ----------------
        FRAG pa0, pa1;
        pa0.u4 = *(const uint4*)(L + P0 + SWZ(wv * 16 + r15, gsl));
        pa1.u4 = *(const uint4*)(L + P0 + SWZ(wv * 16 + r15, 4 + gsl));
        f32x4 oacc[4];
#pragma unroll
        for (int ct = 0; ct < 4; ++ct) {
            FRAG b0, b1;
            b0.u4 = *(const uint4*)(L + VT0 + SWZ(ct * 16 + r15, gsl));
            b1.u4 = *(const uint4*)(L + VT0 + SWZ(ct * 16 + r15, 4 + gsl));
            oacc[ct] = __builtin_amdgcn_mfma_f32_16x16x32_bf16(pa0.s8, b0.s8, zf, 0, 0, 0);
            oacc[ct] = __builtin_amdgcn_mfma_f32_16x16x32_bf16(pa1.s8, b1.s8, oacc[ct], 0, 0, 0);
        }

        // pre[token = q*4 + s][ (n&1)*16 + hd ]  (wave-private rows)
#pragma unroll
        for (int ct = 0; ct < 4; ++ct)
#pragma unroll
            for (int r = 0; r < 4; ++r) {
                const int token = ((qr0 + r) << 2) + ct;
                *(unsigned short*)(L + PR0 + token * 64 + (((n & 1) << 4) + r15) * 2)
                    = f2b(oacc[ct][r]);
            }

        // ---------------- partial projection per head-pair ----------------
        if (n & 1) {
            LGKM_FENCE();                    // pre rows are wave-private
            const int m = n >> 1;
            FRAG pa[4];
#pragma unroll
            for (int rt = 0; rt < 4; ++rt) {
                const int row = (wv << 6) + (rt << 4) + r15;
                pa[rt].u4 = *(const uint4*)(L + PR0 + row * 64 + (gsl << 4));
            }
#pragma unroll
            for (int ct = 0; ct < 6; ++ct) {
                const int o = (ct << 4) + r15;
                const float4* wp = (const float4*)(gpw + o * 96 + (m << 5) + (gsl << 3));
                float4 w0 = wp[0], w1 = wp[1];
                float w8[8] = {w0.x, w0.y, w0.z, w0.w, w1.x, w1.y, w1.z, w1.w};
                FRAG bw;
                bw.u4 = pack8(w8);
#pragma unroll
                for (int rt = 0; rt < 4; ++rt)
                    pacc[rt][ct] = __builtin_amdgcn_mfma_f32_16x16x32_bf16(
                        pa[rt].s8, bw.s8, pacc[rt][ct], 0, 0, 0);
            }
        }
        __syncthreads();                     // barrier 2: cross-wave K/VT reads done
    }

    // ---- epilogue: +bias, per-wave LDS restage (gsq-contiguous), coalesced ----
    {
        const int ep = wv * 6400;
        float pbv[6];
#pragma unroll
        for (int ct = 0; ct < 6; ++ct) pbv[ct] = gpb[ct * 16 + r15];
#pragma unroll
        for (int rt = 0; rt < 4; ++rt) {
#pragma unroll
            for (int ct = 0; ct < 6; ++ct)
#pragma unroll
                for (int r = 0; r < 4; ++r) {
                    const int li = ((r >> 1) << 3) + (gsl << 1) + (r & 1);
                    *(float*)(L + ep + li * 400 + (((ct << 4) + r15) << 2))
                        = pacc[rt][ct][r] + pbv[ct];
                }
            LGKM_FENCE();                    // buffer is wave-private
            const size_t gb = (size_t)w * 256 + ((2 * wv + (rt >> 1)) << 5) + ((rt & 1) << 3);
#pragma unroll
            for (int j = 0; j < 6; ++j) {
                const int f = j * 64 + lane;
                const int li_c = f / 24;
                const int c4 = f - li_c * 24;
                float4 val = *(const float4*)(L + ep + li_c * 400 + (c4 << 4));
                const int gsq_add = ((li_c >> 3) << 4) + (li_c & 7);
                *(float4*)(gout + (gb + gsq_add) * 96 + (c4 << 2)) = val;
            }
            LGKM_FENCE();                    // WAR: reads done before next rt writes
        }
    }
}

extern "C" void kernel_launch(void* const* d_in, const int* in_sizes, int n_in,
                              void* d_out, int out_size, void* d_ws, size_t ws_size,
                              hipStream_t stream) {
    const float* gq     = (const float*)d_in[0];
    const float* gk     = (const float*)d_in[1];
    const float* gv     = (const float*)d_in[2];
    const float* gmask  = (const float*)d_in[3];
    const float* gbt    = (const float*)d_in[4];
    const float* ggamma = (const float*)d_in[5];
    const float* gbeta  = (const float*)d_in[6];
    const float* gpw    = (const float*)d_in[7];
    const float* gpb    = (const float*)d_in[8];
    float* gout = (float*)d_out;

    const int nw  = in_sizes[0] / (256 * 96);
    const int nwm = in_sizes[3] / (64 * 64);

    dwa_mfma<<<nw, TPB, 0, stream>>>(gq, gk, gv, gmask, gbt, ggamma, gbeta,
                                     gpw, gpb, gout, nwm);
}

// Round 6
// 376.270 us; speedup vs baseline: 1.6734x; 1.6734x over previous
//
#include <hip/hip_runtime.h>
#include <hip/hip_bf16.h>

// DiagonalWindowAttention fused MFMA kernel (v4: spill elimination).
// Pre-kernel folds mask+bias into comb[mi][n][q][k] (d_ws). Main kernel:
// one block per window, 256 threads = 4 waves, LB(256,3), LDS 43 KB.
//   head n : stage qn/k (swz bf16 [64][64]) + VT (V transposed, swz) ->
//            QK^T MFMA with C initialized from comb -> softmax in-place ->
//            P overlaid on Q0 (wave-private, lgkm fence) -> PV MFMA ->
//            pre[256][32] -> [odd n: proj MFMA accumulate into pacc]
//   epilogue: +bias, per-wave LDS restage, fully coalesced dwordx4 stores
//
// token grouping: p = wh*8+ww, s = sh*2+sw, seq g = wh*32+sh*16+ww*2+sw

#define TPB 256

// LDS byte offsets
#define Q0   0        // [64][64] bf16 swizzled (8 KB); P overlays after QK^T
#define K0   8192
#define VT0  16384    // V^T per head: [n'=s*16+c][kp] bf16 swizzled (8 KB)
#define PR0  24576    // pre[256][32] bf16 (16 KB)
#define GA0  40960    // gamma fp32 [4][96]
#define BE0  42496    // beta  fp32 [4][96]
#define LDS_TOTAL 44032
// epilogue reuses [0, 25600): per-wave 6400 B at wv*6400 (after final barrier)

typedef __attribute__((ext_vector_type(8))) short short8;
typedef __attribute__((ext_vector_type(4))) float f32x4;

union FRAG { uint4 u4; short8 s8; unsigned short us[8]; };

__device__ __forceinline__ int seq_of(int p, int s) {
    return ((p >> 3) << 5) | ((s >> 1) << 4) | ((p & 7) << 1) | (s & 1);
}

// swizzled byte address of 16B slot in a [64][64] bf16 tile (128B rows)
#define SWZ(row, slot) (((row) << 7) + ((((slot) ^ ((row) & 7))) << 4))

#define LGKM_FENCE() do { \
    asm volatile("s_waitcnt lgkmcnt(0)" ::: "memory"); \
    __builtin_amdgcn_sched_barrier(0); } while (0)

__device__ __forceinline__ unsigned short f2b(float x) {
    union { __hip_bfloat16 h; unsigned short u; } z;
    z.h = __float2bfloat16(x);
    return z.u;
}

__device__ __forceinline__ uint4 pack8(const float* v) {
    union { uint4 u4; unsigned short us[8]; } z;
#pragma unroll
    for (int i = 0; i < 8; ++i) z.us[i] = f2b(v[i]);
    return z.u4;
}

// ---------------- pre-kernel: comb = mask + rel-pos bias ----------------
__global__ void build_comb(const float* __restrict__ gmask,
                           const float* __restrict__ gbt,
                           float* __restrict__ comb) {
    const int b = blockIdx.x;            // b = mi*6 + n
    const int mi = b / 6, n = b - mi * 6;
    const int t = threadIdx.x;
    const float* mrow = gmask + (size_t)mi * 4096;
    float* crow = comb + (size_t)b * 4096;
#pragma unroll
    for (int e = 0; e < 4096; e += TPB) {
        const int i = e + t;
        const int q = i >> 6, k = i & 63;
        const int idx = ((q >> 3) - (k >> 3) + 7) * 15 + ((q & 7) - (k & 7) + 7);
        crow[i] = mrow[i] + gbt[idx * 6 + n];
    }
}

template <int USE_COMB>
__global__ __launch_bounds__(TPB, 3)
void dwa_mfma(const float* __restrict__ gq,
              const float* __restrict__ gk,
              const float* __restrict__ gv,
              const float* __restrict__ gmask,
              const float* __restrict__ gbt,
              const float* __restrict__ ggamma,
              const float* __restrict__ gbeta,
              const float* __restrict__ gpw,
              const float* __restrict__ gpb,
              float* __restrict__ gout,
              const float* __restrict__ comb,
              int nwm)
{
    __shared__ __align__(16) unsigned char Lraw[LDS_TOTAL];
    char* L = (char*)Lraw;

    const int w = blockIdx.x;
    const int t = threadIdx.x;
    const int lane = t & 63, wv = t >> 6;
    const int r15 = lane & 15, gsl = lane >> 4;

    const int p_a = t >> 2, s_a = t & 3;
    const int g_a = seq_of(p_a, s_a);
    const size_t rowbase = ((size_t)w * 256 + g_a) * 96;
    const int mbase = (w % nwm) * 4096;

    float* s_ga = (float*)(L + GA0);
    float* s_be = (float*)(L + BE0);

    // ---------------- phase 0: LN stats (regs) + gamma/beta ----------------
    float mu, rs;
    {
        const float4* qr = (const float4*)(gq + rowbase);
        float sum = 0.f, ssq = 0.f;
#pragma unroll
        for (int i = 0; i < 24; ++i) {
            float4 x = qr[i];
            sum += (x.x + x.y) + (x.z + x.w);
            ssq += (x.x * x.x + x.y * x.y) + (x.z * x.z + x.w * x.w);
        }
        sum += __shfl_xor(sum, 1); ssq += __shfl_xor(ssq, 1);
        sum += __shfl_xor(sum, 2); ssq += __shfl_xor(ssq, 2);
        mu = sum * (1.f / 384.f);
        rs = rsqrtf(ssq * (1.f / 384.f) - mu * mu + 1e-5f);
    }
    for (int i = t; i < 384; i += TPB) {
        s_ga[i] = ggamma[i];
        s_be[i] = gbeta[i];
    }
    __syncthreads();
    const float* gaT = s_ga + s_a * 96;
    const float* beT = s_be + s_a * 96;

    const f32x4 zf = {0.f, 0.f, 0.f, 0.f};
    f32x4 pacc[4][6];
#pragma unroll
    for (int a = 0; a < 4; ++a)
#pragma unroll
        for (int b = 0; b < 6; ++b) pacc[a][b] = zf;

    const int qr0 = (wv << 4) + (gsl << 2);   // C-layout q-row base (+reg)

    for (int n = 0; n < 6; ++n) {
        // ------- stage q (LN'd) / k row-major swz, V transposed -------
        {
            const float* qs = gq + rowbase + n * 16;
            const float* ks = gk + rowbase + n * 16;
            const float* vs = gv + rowbase + n * 16;
#pragma unroll
            for (int h = 0; h < 2; ++h) {
                float4 q0 = ((const float4*)qs)[2 * h], q1 = ((const float4*)qs)[2 * h + 1];
                float4 k0 = ((const float4*)ks)[2 * h], k1 = ((const float4*)ks)[2 * h + 1];
                float4 v0 = ((const float4*)vs)[2 * h], v1 = ((const float4*)vs)[2 * h + 1];
                float qv[8] = {q0.x, q0.y, q0.z, q0.w, q1.x, q1.y, q1.z, q1.w};
                float kv[8] = {k0.x, k0.y, k0.z, k0.w, k1.x, k1.y, k1.z, k1.w};
                float vv[8] = {v0.x, v0.y, v0.z, v0.w, v1.x, v1.y, v1.z, v1.w};
                const float* ga = gaT + n * 16 + h * 8;
                const float* be = beT + n * 16 + h * 8;
#pragma unroll
                for (int i = 0; i < 8; ++i)
                    qv[i] = ((qv[i] - mu) * rs * ga[i] + be[i]) * 0.125f;
                *(uint4*)(L + Q0 + SWZ(p_a, s_a * 2 + h)) = pack8(qv);
                *(uint4*)(L + K0 + SWZ(p_a, s_a * 2 + h)) = pack8(kv);
#pragma unroll
                for (int c = 0; c < 8; ++c) {
                    const int np_ = s_a * 16 + h * 8 + c;   // n' row of VT
                    *(unsigned short*)(L + VT0 + (np_ << 7) +
                        ((((p_a >> 3) ^ (np_ & 7))) << 4) + ((p_a & 7) << 1)) = f2b(vv[c]);
                }
            }
        }
        __syncthreads();                     // barrier 1: staging visible

        // ------- QK^T with C initialized from comb (bias+mask) -------
        f32x4 sacc[4];
        if (USE_COMB) {
            const float* cb = comb + (size_t)((w % nwm) * 6 + n) * 4096;
#pragma unroll
            for (int tile = 0; tile < 4; ++tile)
#pragma unroll
                for (int r = 0; r < 4; ++r)
                    sacc[tile][r] = cb[((qr0 + r) << 6) + (tile << 4) + r15];
        } else {
#pragma unroll
            for (int tile = 0; tile < 4; ++tile) {
                const int kpx = (tile << 4) + r15;
                const int ik = kpx >> 3, jk = kpx & 7;
#pragma unroll
                for (int r = 0; r < 4; ++r) {
                    const int q = qr0 + r;
                    sacc[tile][r] = gbt[(((q >> 3) - ik + 7) * 15 + ((q & 7) - jk + 7)) * 6 + n]
                                  + gmask[mbase + (q << 6) + kpx];
                }
            }
        }
        {
            FRAG a0, a1;
            a0.u4 = *(const uint4*)(L + Q0 + SWZ(wv * 16 + r15, gsl));
            a1.u4 = *(const uint4*)(L + Q0 + SWZ(wv * 16 + r15, 4 + gsl));
#pragma unroll
            for (int tile = 0; tile < 4; ++tile) {
                FRAG b0, b1;
                b0.u4 = *(const uint4*)(L + K0 + SWZ(tile * 16 + r15, gsl));
                b1.u4 = *(const uint4*)(L + K0 + SWZ(tile * 16 + r15, 4 + gsl));
                sacc[tile] = __builtin_amdgcn_mfma_f32_16x16x32_bf16(a0.s8, b0.s8, sacc[tile], 0, 0, 0);
                sacc[tile] = __builtin_amdgcn_mfma_f32_16x16x32_bf16(a1.s8, b1.s8, sacc[tile], 0, 0, 0);
            }
        }

        // ------- softmax in place; P stored over Q0 (wave-private rows) -------
#pragma unroll
        for (int r = 0; r < 4; ++r) {
            const int q = qr0 + r;
            float mx = fmaxf(fmaxf(sacc[0][r], sacc[1][r]),
                             fmaxf(sacc[2][r], sacc[3][r]));
            mx = fmaxf(mx, __shfl_xor(mx, 1));
            mx = fmaxf(mx, __shfl_xor(mx, 2));
            mx = fmaxf(mx, __shfl_xor(mx, 4));
            mx = fmaxf(mx, __shfl_xor(mx, 8));
            float sm = 0.f;
#pragma unroll
            for (int tile = 0; tile < 4; ++tile) {
                sacc[tile][r] = __expf(sacc[tile][r] - mx);
                sm += sacc[tile][r];
            }
            sm += __shfl_xor(sm, 1);
            sm += __shfl_xor(sm, 2);
            sm += __shfl_xor(sm, 4);
            sm += __shfl_xor(sm, 8);
            const float inv = 1.0f / sm;
#pragma unroll
            for (int tile = 0; tile < 4; ++tile) {
                const int col = (tile << 4) + r15;
                *(unsigned short*)(L + Q0 + (q << 7) +
                                   (((col >> 3) ^ (q & 7)) << 4) + ((col & 7) << 1))
                    = f2b(sacc[tile][r] * inv);
            }
        }
        LGKM_FENCE();                        // P rows are wave-private

        // ------- PV: A-frags = P (from Q0), B-frags = VT rows -------
        f32x4 oacc[4];
        {
            FRAG pa0, pa1;
            pa0.u4 = *(const uint4*)(L + Q0 + SWZ(wv * 16 + r15, gsl));
            pa1.u4 = *(const uint4*)(L + Q0 + SWZ(wv * 16 + r15, 4 + gsl));
#pragma unroll
            for (int ct = 0; ct < 4; ++ct) {
                FRAG b0, b1;
                b0.u4 = *(const uint4*)(L + VT0 + SWZ(ct * 16 + r15, gsl));
                b1.u4 = *(const uint4*)(L + VT0 + SWZ(ct * 16 + r15, 4 + gsl));
                oacc[ct] = __builtin_amdgcn_mfma_f32_16x16x32_bf16(pa0.s8, b0.s8, zf, 0, 0, 0);
                oacc[ct] = __builtin_amdgcn_mfma_f32_16x16x32_bf16(pa1.s8, b1.s8, oacc[ct], 0, 0, 0);
            }
        }

        // pre[token = q*4 + s][ (n&1)*16 + hd ]  (wave-private rows)
#pragma unroll
        for (int ct = 0; ct < 4; ++ct)
#pragma unroll
            for (int r = 0; r < 4; ++r) {
                const int token = ((qr0 + r) << 2) + ct;
                *(unsigned short*)(L + PR0 + token * 64 + (((n & 1) << 4) + r15) * 2)
                    = f2b(oacc[ct][r]);
            }

        // ------- partial projection per head-pair -------
        if (n & 1) {
            LGKM_FENCE();                    // pre rows are wave-private
            const int m = n >> 1;
            FRAG pa[4];
#pragma unroll
            for (int rt = 0; rt < 4; ++rt) {
                const int row = (wv << 6) + (rt << 4) + r15;
                pa[rt].u4 = *(const uint4*)(L + PR0 + row * 64 + (gsl << 4));
            }
#pragma unroll
            for (int ct = 0; ct < 6; ++ct) {
                const int o = (ct << 4) + r15;
                const float4* wp = (const float4*)(gpw + o * 96 + (m << 5) + (gsl << 3));
                float4 w0 = wp[0], w1 = wp[1];
                float w8[8] = {w0.x, w0.y, w0.z, w0.w, w1.x, w1.y, w1.z, w1.w};
                FRAG bw;
                bw.u4 = pack8(w8);
#pragma unroll
                for (int rt = 0; rt < 4; ++rt)
                    pacc[rt][ct] = __builtin_amdgcn_mfma_f32_16x16x32_bf16(
                        pa[rt].s8, bw.s8, pacc[rt][ct], 0, 0, 0);
            }
        }
        __syncthreads();                     // barrier 2: cross-wave reads done
    }

    // ---- epilogue: +bias, per-wave LDS restage (gsq-contiguous), coalesced ----
    {
        const int ep = wv * 6400;
        float pbv[6];
#pragma unroll
        for (int ct = 0; ct < 6; ++ct) pbv[ct] = gpb[ct * 16 + r15];
#pragma unroll
        for (int rt = 0; rt < 4; ++rt) {
#pragma unroll
            for (int ct = 0; ct < 6; ++ct)
#pragma unroll
                for (int r = 0; r < 4; ++r) {
                    const int li = ((r >> 1) << 3) + (gsl << 1) + (r & 1);
                    *(float*)(L + ep + li * 400 + (((ct << 4) + r15) << 2))
                        = pacc[rt][ct][r] + pbv[ct];
                }
            LGKM_FENCE();                    // buffer is wave-private
            const size_t gb = (size_t)w * 256 + ((2 * wv + (rt >> 1)) << 5) + ((rt & 1) << 3);
#pragma unroll
            for (int j = 0; j < 6; ++j) {
                const int f = j * 64 + lane;
                const int li_c = f / 24;
                const int c4 = f - li_c * 24;
                float4 val = *(const float4*)(L + ep + li_c * 400 + (c4 << 4));
                const int gsq_add = ((li_c >> 3) << 4) + (li_c & 7);
                *(float4*)(gout + (gb + gsq_add) * 96 + (c4 << 2)) = val;
            }
            LGKM_FENCE();                    // WAR before next rt overwrite
        }
    }
}

extern "C" void kernel_launch(void* const* d_in, const int* in_sizes, int n_in,
                              void* d_out, int out_size, void* d_ws, size_t ws_size,
                              hipStream_t stream) {
    const float* gq     = (const float*)d_in[0];
    const float* gk     = (const float*)d_in[1];
    const float* gv     = (const float*)d_in[2];
    const float* gmask  = (const float*)d_in[3];
    const float* gbt    = (const float*)d_in[4];
    const float* ggamma = (const float*)d_in[5];
    const float* gbeta  = (const float*)d_in[6];
    const float* gpw    = (const float*)d_in[7];
    const float* gpb    = (const float*)d_in[8];
    float* gout = (float*)d_out;

    const int nw  = in_sizes[0] / (256 * 96);
    const int nwm = in_sizes[3] / (64 * 64);
    const size_t comb_bytes = (size_t)nwm * 6 * 4096 * sizeof(float);

    if (ws_size >= comb_bytes) {
        float* comb = (float*)d_ws;
        build_comb<<<nwm * 6, TPB, 0, stream>>>(gmask, gbt, comb);
        dwa_mfma<1><<<nw, TPB, 0, stream>>>(gq, gk, gv, gmask, gbt, ggamma, gbeta,
                                            gpw, gpb, gout, comb, nwm);
    } else {
        dwa_mfma<0><<<nw, TPB, 0, stream>>>(gq, gk, gv, gmask, gbt, ggamma, gbeta,
                                            gpw, gpb, gout, (const float*)nullptr, nwm);
    }
}

// Round 7
// 274.076 us; speedup vs baseline: 2.2973x; 1.3729x over previous
//
#include <hip/hip_runtime.h>
#include <hip/hip_bf16.h>

// DiagonalWindowAttention fused MFMA kernel (v5: no spills, single q read,
// deferred projection, K/V register prefetch).
// One block per window (nw=2048), 256 threads = 4 waves, LB(256,2), LDS 76 KB.
//   phase 0 : load q fully to regs, LN stats (shfl), LN+pack -> 12 uint4 regs;
//             prefetch head-0 k/v into regs. NO barrier.
//   head n  : stage Q (from regs) / K (prefetched) swz bf16 [64][64], VT
//             (V transposed, swz); prefetch head n+1 k/v; load comb -> sacc;
//             sync; QK^T MFMA (C=comb) -> softmax -> P over Q0 (wave-private,
//             fence) -> PV MFMA -> pre into PR[256][104] bf16; sync.
//   epilogue: per wave, 4 sequential 16-token M-tiles: PR A-frags x W B-frags
//             (built once) -> 18 MFMA -> +bias -> scalar stores via seq_of.
//
// token grouping: p = wh*8+ww, s = sh*2+sw, seq g = wh*32+sh*16+ww*2+sw

#define TPB 256

// LDS byte offsets
#define Q0   0        // [64][64] bf16 swizzled (8 KB); P overlays after QK^T
#define K0   8192
#define VT0  16384    // V^T per head: [n'=s*16+c][kp] bf16 swizzled (8 KB)
#define PR0  24576    // pre[256 tokens][104 shorts] (208 B rows) = 53248 B
#define LDS_TOTAL 77824

typedef __attribute__((ext_vector_type(8))) short short8;
typedef __attribute__((ext_vector_type(4))) float f32x4;

union FRAG { uint4 u4; short8 s8; unsigned short us[8]; };

__device__ __forceinline__ int seq_of(int p, int s) {
    return ((p >> 3) << 5) | ((s >> 1) << 4) | ((p & 7) << 1) | (s & 1);
}

// swizzled byte address of 16B slot in a [64][64] bf16 tile (128B rows)
#define SWZ(row, slot) (((row) << 7) + ((((slot) ^ ((row) & 7))) << 4))

#define LGKM_FENCE() do { \
    asm volatile("s_waitcnt lgkmcnt(0)" ::: "memory"); \
    __builtin_amdgcn_sched_barrier(0); } while (0)

__device__ __forceinline__ unsigned short f2b(float x) {
    union { __hip_bfloat16 h; unsigned short u; } z;
    z.h = __float2bfloat16(x);
    return z.u;
}

__device__ __forceinline__ uint4 pack8(const float* v) {
    union { uint4 u4; unsigned short us[8]; } z;
#pragma unroll
    for (int i = 0; i < 8; ++i) z.us[i] = f2b(v[i]);
    return z.u4;
}

// load 16 floats (4x float4), pack to 2x uint4 (bf16 x16)
__device__ __forceinline__ void load_pack(const float* src, uint4* dst) {
    float v[16];
#pragma unroll
    for (int i = 0; i < 4; ++i) {
        float4 x = ((const float4*)src)[i];
        v[4 * i] = x.x; v[4 * i + 1] = x.y; v[4 * i + 2] = x.z; v[4 * i + 3] = x.w;
    }
    dst[0] = pack8(v);
    dst[1] = pack8(v + 8);
}

// ---------------- pre-kernel: comb = mask + rel-pos bias ----------------
__global__ void build_comb(const float* __restrict__ gmask,
                           const float* __restrict__ gbt,
                           float* __restrict__ comb) {
    const int b = blockIdx.x;            // b = mi*6 + n
    const int mi = b / 6, n = b - mi * 6;
    const int t = threadIdx.x;
    const float* mrow = gmask + (size_t)mi * 4096;
    float* crow = comb + (size_t)b * 4096;
#pragma unroll
    for (int e = 0; e < 4096; e += TPB) {
        const int i = e + t;
        const int q = i >> 6, k = i & 63;
        const int idx = ((q >> 3) - (k >> 3) + 7) * 15 + ((q & 7) - (k & 7) + 7);
        crow[i] = mrow[i] + gbt[idx * 6 + n];
    }
}

template <int USE_COMB>
__global__ __launch_bounds__(TPB, 2)
void dwa_mfma(const float* __restrict__ gq,
              const float* __restrict__ gk,
              const float* __restrict__ gv,
              const float* __restrict__ gmask,
              const float* __restrict__ gbt,
              const float* __restrict__ ggamma,
              const float* __restrict__ gbeta,
              const float* __restrict__ gpw,
              const float* __restrict__ gpb,
              float* __restrict__ gout,
              const float* __restrict__ comb,
              int nwm)
{
    __shared__ __align__(16) unsigned char Lraw[LDS_TOTAL];
    char* L = (char*)Lraw;

    const int w = blockIdx.x;
    const int t = threadIdx.x;
    const int lane = t & 63, wv = t >> 6;
    const int r15 = lane & 15, gsl = lane >> 4;

    const int p_a = t >> 2, s_a = t & 3;
    const int g_a = seq_of(p_a, s_a);
    const size_t rowbase = ((size_t)w * 256 + g_a) * 96;
    const int mbase = (w % nwm) * 4096;
    const int qr0 = (wv << 4) + (gsl << 2);   // C-layout q-row base (+reg)
    const f32x4 zf = {0.f, 0.f, 0.f, 0.f};

    // ---------- phase 0: q full load, LN stats, LN+pack to regs ----------
    uint4 qreg[12];
    {
        float qv[96];
        float sum = 0.f, ssq = 0.f;
        const float4* qr4 = (const float4*)(gq + rowbase);
#pragma unroll
        for (int i = 0; i < 24; ++i) {
            float4 x = qr4[i];
            qv[4 * i] = x.x; qv[4 * i + 1] = x.y;
            qv[4 * i + 2] = x.z; qv[4 * i + 3] = x.w;
            sum += (x.x + x.y) + (x.z + x.w);
            ssq += (x.x * x.x + x.y * x.y) + (x.z * x.z + x.w * x.w);
        }
        sum += __shfl_xor(sum, 1); ssq += __shfl_xor(ssq, 1);
        sum += __shfl_xor(sum, 2); ssq += __shfl_xor(ssq, 2);
        const float mu = sum * (1.f / 384.f);
        const float rs = rsqrtf(ssq * (1.f / 384.f) - mu * mu + 1e-5f);
        const float4* ga4 = (const float4*)(ggamma + s_a * 96);
        const float4* be4 = (const float4*)(gbeta + s_a * 96);
#pragma unroll
        for (int c6 = 0; c6 < 6; ++c6) {      // 16 channels per chunk
            float vals[16];
#pragma unroll
            for (int j = 0; j < 4; ++j) {
                float4 g = ga4[c6 * 4 + j];
                float4 b = be4[c6 * 4 + j];
                const int base = c6 * 16 + 4 * j;
                vals[4 * j + 0] = ((qv[base + 0] - mu) * rs * g.x + b.x) * 0.125f;
                vals[4 * j + 1] = ((qv[base + 1] - mu) * rs * g.y + b.y) * 0.125f;
                vals[4 * j + 2] = ((qv[base + 2] - mu) * rs * g.z + b.z) * 0.125f;
                vals[4 * j + 3] = ((qv[base + 3] - mu) * rs * g.w + b.w) * 0.125f;
            }
            qreg[2 * c6]     = pack8(vals);
            qreg[2 * c6 + 1] = pack8(vals + 8);
        }
    }

    // prefetch head-0 k/v
    uint4 kpf[2][2], vpf[2][2];
    load_pack(gk + rowbase, kpf[0]);
    load_pack(gv + rowbase, vpf[0]);

    // -------------------------- head loop --------------------------
#pragma unroll
    for (int n = 0; n < 6; ++n) {
        // stage Q (regs), K (prefetched), VT (prefetched, transposed)
        *(uint4*)(L + Q0 + SWZ(p_a, s_a * 2))     = qreg[2 * n];
        *(uint4*)(L + Q0 + SWZ(p_a, s_a * 2 + 1)) = qreg[2 * n + 1];
        *(uint4*)(L + K0 + SWZ(p_a, s_a * 2))     = kpf[n & 1][0];
        *(uint4*)(L + K0 + SWZ(p_a, s_a * 2 + 1)) = kpf[n & 1][1];
#pragma unroll
        for (int h = 0; h < 2; ++h) {
            FRAG u; u.u4 = vpf[n & 1][h];
#pragma unroll
            for (int c = 0; c < 8; ++c) {
                const int np_ = s_a * 16 + h * 8 + c;   // n' row of VT
                *(unsigned short*)(L + VT0 + (np_ << 7) +
                    ((((p_a >> 3) ^ (np_ & 7))) << 4) + ((p_a & 7) << 1)) = u.us[c];
            }
        }
        // prefetch next head's k/v (hidden under this head's compute)
        if (n < 5) {
            load_pack(gk + rowbase + (n + 1) * 16, kpf[(n + 1) & 1]);
            load_pack(gv + rowbase + (n + 1) * 16, vpf[(n + 1) & 1]);
        }
        // C-init (bias+mask) issued before the barrier for latency overlap
        f32x4 sacc[4];
        if (USE_COMB) {
            const float* cb = comb + (size_t)((w % nwm) * 6 + n) * 4096;
#pragma unroll
            for (int tile = 0; tile < 4; ++tile)
#pragma unroll
                for (int r = 0; r < 4; ++r)
                    sacc[tile][r] = cb[((qr0 + r) << 6) + (tile << 4) + r15];
        } else {
#pragma unroll
            for (int tile = 0; tile < 4; ++tile) {
                const int kpx = (tile << 4) + r15;
                const int ik = kpx >> 3, jk = kpx & 7;
#pragma unroll
                for (int r = 0; r < 4; ++r) {
                    const int q = qr0 + r;
                    sacc[tile][r] = gbt[(((q >> 3) - ik + 7) * 15 + ((q & 7) - jk + 7)) * 6 + n]
                                  + gmask[mbase + (q << 6) + kpx];
                }
            }
        }
        __syncthreads();                     // barrier 1: staging visible

        // QK^T (C = comb)
        {
            FRAG a0, a1;
            a0.u4 = *(const uint4*)(L + Q0 + SWZ(wv * 16 + r15, gsl));
            a1.u4 = *(const uint4*)(L + Q0 + SWZ(wv * 16 + r15, 4 + gsl));
#pragma unroll
            for (int tile = 0; tile < 4; ++tile) {
                FRAG b0, b1;
                b0.u4 = *(const uint4*)(L + K0 + SWZ(tile * 16 + r15, gsl));
                b1.u4 = *(const uint4*)(L + K0 + SWZ(tile * 16 + r15, 4 + gsl));
                sacc[tile] = __builtin_amdgcn_mfma_f32_16x16x32_bf16(a0.s8, b0.s8, sacc[tile], 0, 0, 0);
                sacc[tile] = __builtin_amdgcn_mfma_f32_16x16x32_bf16(a1.s8, b1.s8, sacc[tile], 0, 0, 0);
            }
        }

        // softmax in place; P stored over Q0 (wave-private rows)
#pragma unroll
        for (int r = 0; r < 4; ++r) {
            const int q = qr0 + r;
            float mx = fmaxf(fmaxf(sacc[0][r], sacc[1][r]),
                             fmaxf(sacc[2][r], sacc[3][r]));
            mx = fmaxf(mx, __shfl_xor(mx, 1));
            mx = fmaxf(mx, __shfl_xor(mx, 2));
            mx = fmaxf(mx, __shfl_xor(mx, 4));
            mx = fmaxf(mx, __shfl_xor(mx, 8));
            float sm = 0.f;
#pragma unroll
            for (int tile = 0; tile < 4; ++tile) {
                sacc[tile][r] = __expf(sacc[tile][r] - mx);
                sm += sacc[tile][r];
            }
            sm += __shfl_xor(sm, 1);
            sm += __shfl_xor(sm, 2);
            sm += __shfl_xor(sm, 4);
            sm += __shfl_xor(sm, 8);
            const float inv = 1.0f / sm;
#pragma unroll
            for (int tile = 0; tile < 4; ++tile) {
                const int col = (tile << 4) + r15;
                *(unsigned short*)(L + Q0 + (q << 7) +
                                   (((col >> 3) ^ (q & 7)) << 4) + ((col & 7) << 1))
                    = f2b(sacc[tile][r] * inv);
            }
        }
        LGKM_FENCE();                        // P rows are wave-private

        // PV: A-frags = P (from Q0), B-frags = VT rows
        f32x4 oacc[4];
        {
            FRAG pa0, pa1;
            pa0.u4 = *(const uint4*)(L + Q0 + SWZ(wv * 16 + r15, gsl));
            pa1.u4 = *(const uint4*)(L + Q0 + SWZ(wv * 16 + r15, 4 + gsl));
#pragma unroll
            for (int ct = 0; ct < 4; ++ct) {
                FRAG b0, b1;
                b0.u4 = *(const uint4*)(L + VT0 + SWZ(ct * 16 + r15, gsl));
                b1.u4 = *(const uint4*)(L + VT0 + SWZ(ct * 16 + r15, 4 + gsl));
                oacc[ct] = __builtin_amdgcn_mfma_f32_16x16x32_bf16(pa0.s8, b0.s8, zf, 0, 0, 0);
                oacc[ct] = __builtin_amdgcn_mfma_f32_16x16x32_bf16(pa1.s8, b1.s8, oacc[ct], 0, 0, 0);
            }
        }

        // pre[token = q*4 + s][ n*16 + hd ] into PR (208 B rows)
#pragma unroll
        for (int ct = 0; ct < 4; ++ct)
#pragma unroll
            for (int r = 0; r < 4; ++r) {
                const int token = ((qr0 + r) << 2) + ct;
                *(unsigned short*)(L + PR0 + token * 208 + ((n << 4) + r15) * 2)
                    = f2b(oacc[ct][r]);
            }
        __syncthreads();                     // barrier 2: cross-wave reads done
    }

    // ------ epilogue: deferred projection, 4 sequential M-tiles per wave ------
    {
        // W B-frags: o = ct*16 + r15, channels kk*32 + gsl*8 .. +8
        FRAG bw[3][6];
#pragma unroll
        for (int kk = 0; kk < 3; ++kk)
#pragma unroll
            for (int ct = 0; ct < 6; ++ct) {
                const int o = (ct << 4) + r15;
                const float4* wp = (const float4*)(gpw + o * 96 + kk * 32 + (gsl << 3));
                float4 w0 = wp[0], w1 = wp[1];
                float w8[8] = {w0.x, w0.y, w0.z, w0.w, w1.x, w1.y, w1.z, w1.w};
                bw[kk][ct].u4 = pack8(w8);
            }
        float pbv[6];
#pragma unroll
        for (int ct = 0; ct < 6; ++ct) pbv[ct] = gpb[(ct << 4) + r15];

#pragma unroll
        for (int mt = 0; mt < 4; ++mt) {
            const int rowA = (wv << 6) + (mt << 4) + r15;
            FRAG A[3];
#pragma unroll
            for (int kk = 0; kk < 3; ++kk)
                A[kk].u4 = *(const uint4*)(L + PR0 + rowA * 208 + kk * 64 + (gsl << 4));
            f32x4 acc[6];
#pragma unroll
            for (int ct = 0; ct < 6; ++ct) {
                acc[ct] = __builtin_amdgcn_mfma_f32_16x16x32_bf16(A[0].s8, bw[0][ct].s8, zf, 0, 0, 0);
                acc[ct] = __builtin_amdgcn_mfma_f32_16x16x32_bf16(A[1].s8, bw[1][ct].s8, acc[ct], 0, 0, 0);
                acc[ct] = __builtin_amdgcn_mfma_f32_16x16x32_bf16(A[2].s8, bw[2][ct].s8, acc[ct], 0, 0, 0);
            }
#pragma unroll
            for (int ct = 0; ct < 6; ++ct)
#pragma unroll
                for (int rr = 0; rr < 4; ++rr) {
                    const int token = (wv << 6) + (mt << 4) + (gsl << 2) + rr;
                    const int p = token >> 2, s = token & 3;
                    const int gsq = seq_of(p, s);
                    gout[((size_t)w * 256 + gsq) * 96 + (ct << 4) + r15]
                        = acc[ct][rr] + pbv[ct];
                }
        }
    }
}

extern "C" void kernel_launch(void* const* d_in, const int* in_sizes, int n_in,
                              void* d_out, int out_size, void* d_ws, size_t ws_size,
                              hipStream_t stream) {
    const float* gq     = (const float*)d_in[0];
    const float* gk     = (const float*)d_in[1];
    const float* gv     = (const float*)d_in[2];
    const float* gmask  = (const float*)d_in[3];
    const float* gbt    = (const float*)d_in[4];
    const float* ggamma = (const float*)d_in[5];
    const float* gbeta  = (const float*)d_in[6];
    const float* gpw    = (const float*)d_in[7];
    const float* gpb    = (const float*)d_in[8];
    float* gout = (float*)d_out;

    const int nw  = in_sizes[0] / (256 * 96);
    const int nwm = in_sizes[3] / (64 * 64);
    const size_t comb_bytes = (size_t)nwm * 6 * 4096 * sizeof(float);

    if (ws_size >= comb_bytes) {
        float* comb = (float*)d_ws;
        build_comb<<<nwm * 6, TPB, 0, stream>>>(gmask, gbt, comb);
        dwa_mfma<1><<<nw, TPB, 0, stream>>>(gq, gk, gv, gmask, gbt, ggamma, gbeta,
                                            gpw, gpb, gout, comb, nwm);
    } else {
        dwa_mfma<0><<<nw, TPB, 0, stream>>>(gq, gk, gv, gmask, gbt, ggamma, gbeta,
                                            gpw, gpb, gout, (const float*)nullptr, nwm);
    }
}